// Round 6
// baseline (244.146 us; speedup 1.0000x reference)
//
#include <hip/hip_runtime.h>
#include <stdint.h>
#include <math.h>

// MultiHeadAttention: B=2, S=2048, D=1024, H=16, DH=64
// R11 (resubmit; previous round failed on container acquisition, not kernel):
//  - KVBLK 128->64: Ks/Vs [2][64*64] (16KB each), LDS 50KB -> 2-3 blocks/CU
//    (was 82KB -> 1 block/CU, 1 wave/SIMD -- the structural stall).
//  - P layout [32 q][72] (pad-72, NO xor swizzle): b64 stores land 4/bank
//    (floor), b128 reads 8/bank (floor). R10's 128B-stride layout was 4-way.
//  - truncation pack (R6-proven u>>16) + lsum from u&0xFFFF0000 reinterpret:
//    ~2 VALU/elem vs R10's ~7; numerator/denominator still use the SAME
//    rounded weights.
// gemm_out: BK=64 + XOR chunk swizzle. prep/proj unchanged (R7).

typedef __attribute__((ext_vector_type(8))) short short8;
typedef __attribute__((ext_vector_type(4))) short short4v;
typedef __attribute__((ext_vector_type(4))) float floatx4;

#define LOG2E 1.44269504088896340736f

__device__ __forceinline__ unsigned short f32_bf16(float f) {
  union { float f; unsigned u; } c; c.f = f;
  return (unsigned short)((c.u + 0x7FFFu + ((c.u >> 16) & 1u)) >> 16);
}
__device__ __forceinline__ float bf16_f32(unsigned short u) {
  union { unsigned u; float f; } c; c.u = ((unsigned)u) << 16;
  return c.f;
}
__device__ __forceinline__ void gld16(const void* g, void* l) {
  __builtin_amdgcn_global_load_lds((const __attribute__((address_space(1))) void*)g,
                                   (__attribute__((address_space(3))) void*)l, 16, 0, 0);
}

// ---------------- prep: cvt inputs + weight transposes + mask, one launch ----------------

__global__ __launch_bounds__(256) void prep_kernel(
    const float* __restrict__ qf, const float* __restrict__ kf, const float* __restrict__ vf,
    const float* __restrict__ w0, const float* __restrict__ w1, const float* __restrict__ w2,
    const float* __restrict__ wo, const int* __restrict__ mask,
    unsigned short* __restrict__ oq, unsigned short* __restrict__ ok, unsigned short* __restrict__ ov,
    unsigned short* __restrict__ o0, unsigned short* __restrict__ o1, unsigned short* __restrict__ o2,
    unsigned short* __restrict__ oo, float* __restrict__ mb) {
  __shared__ float t[32][33];
  const int y = blockIdx.y, bx = blockIdx.x;
  if (y < 3) {
    if (y == 0 && bx < 16) {
      int j = bx * 256 + threadIdx.x;
      mb[j] = (mask[j] == 0) ? (-1.0e9f * LOG2E) : 0.0f;
    }
    const float* in = (y == 0) ? qf : (y == 1) ? kf : vf;
    unsigned short* out = (y == 0) ? oq : (y == 1) ? ok : ov;
    int i = bx * 256 + threadIdx.x;
    float4 v = reinterpret_cast<const float4*>(in)[i];
    ushort4 o;
    o.x = f32_bf16(v.x); o.y = f32_bf16(v.y); o.z = f32_bf16(v.z); o.w = f32_bf16(v.w);
    reinterpret_cast<ushort4*>(out)[i] = o;
    return;
  }
  const int tx = threadIdx.x & 31, ty = threadIdx.x >> 5;
  const float* in; unsigned short* out; int R, C, z, r0, c0;
  if (bx < 3072) {
    const int zb = bx >> 6, rem = bx & 63;
    const int sel = zb >> 4; z = zb & 15;
    in = (sel == 0) ? w0 : (sel == 1) ? w1 : w2;
    out = (sel == 0) ? o0 : (sel == 1) ? o1 : o2;
    R = 1024; C = 64; r0 = (rem >> 1) * 32; c0 = (rem & 1) * 32;
  } else {
    const int t2 = bx - 3072;
    in = wo; out = oo; R = 1024; C = 1024; z = 0;
    r0 = (t2 >> 5) * 32; c0 = (t2 & 31) * 32;
  }
  const float* inp = in + (size_t)z * R * C;
  #pragma unroll
  for (int j = 0; j < 4; ++j)
    t[ty + j * 8][tx] = inp[(size_t)(r0 + ty + j * 8) * C + c0 + tx];
  __syncthreads();
  #pragma unroll
  for (int j = 0; j < 4; ++j)
    out[((size_t)z * C + c0 + ty + j * 8) * R + r0 + tx] = f32_bf16(t[tx][ty + j * 8]);
}

// ---------------- 256x256 deep-pipelined projection GEMM (unchanged R7) ----------------

__global__ __launch_bounds__(512, 2) void gemm_proj_kernel(
    const unsigned short* __restrict__ qin, const unsigned short* __restrict__ kin,
    const unsigned short* __restrict__ vin,
    const unsigned short* __restrict__ WqT, const unsigned short* __restrict__ WkT,
    const unsigned short* __restrict__ WvT,
    const float* __restrict__ bq, const float* __restrict__ bk, const float* __restrict__ bv,
    unsigned short* __restrict__ Qp, unsigned short* __restrict__ Kp,
    unsigned short* __restrict__ Vt) {
  __shared__ unsigned short As[2][2][128 * 64];
  __shared__ unsigned short Bs[2][2][128 * 64];

  const int z = blockIdx.y;
  const int x = blockIdx.x;
  const int r = x & 7, q = x >> 3;
  int mt, nt;
  if (z < 2) { mt = r * 2 + (q >> 2); nt = q & 3; }
  else       { nt = r * 2 + (q >> 2); mt = q & 3; }
  const int blockM = mt * 256, blockN = nt * 256;

  const unsigned short* A  = (z == 0) ? qin : (z == 1) ? kin : WvT;
  const unsigned short* Bt = (z == 0) ? WqT : (z == 1) ? WkT : vin;
  const float* bias = (z == 0) ? bq : (z == 1) ? bk : bv;

  const int tid = threadIdx.x;
  const int w = tid >> 6, lane = tid & 63;
  const int quad = lane >> 4, l15 = lane & 15;
  const int wm = w & 1, wn = w >> 1;

  const int lr8 = lane >> 3;
  const int lc8 = lane & 7;
  const int gcs = lc8 ^ lr8;

  auto stage = [&](int k0, int buf) {
    #pragma unroll
    for (int h = 0; h < 2; ++h)
      #pragma unroll
      for (int s2 = 0; s2 < 2; ++s2) {
        const int rl = s2 * 64 + w * 8;
        gld16(A + (size_t)(blockM + h * 128 + rl + lr8) * 1024 + k0 + gcs * 8,
              &As[buf][h][rl * 64]);
      }
    #pragma unroll
    for (int h = 0; h < 2; ++h)
      #pragma unroll
      for (int s2 = 0; s2 < 2; ++s2) {
        const int rl = s2 * 64 + w * 8;
        gld16(Bt + (size_t)(blockN + h * 128 + rl + lr8) * 1024 + k0 + gcs * 8,
              &Bs[buf][h][rl * 64]);
      }
  };

  floatx4 acc[8][4];
  #pragma unroll
  for (int mi = 0; mi < 8; ++mi)
    #pragma unroll
    for (int ni = 0; ni < 4; ++ni)
      acc[mi][ni] = (floatx4){0.f, 0.f, 0.f, 0.f};

  stage(0, 0);
  __syncthreads();

  const int brb = (wn & 1) * 64;

  for (int st = 0; st < 16; ++st) {
    const int buf = st & 1;
    const unsigned short* Ah = &As[buf][wm][0];
    const unsigned short* Bh = &Bs[buf][wn >> 1][0];
    short8 af[4][2], b0[2][2], b1[2][2];

    if (st + 1 < 16) stage((st + 1) * 64, buf ^ 1);
    #pragma unroll
    for (int mi = 0; mi < 4; ++mi) {
      const int row = mi * 16 + l15;
      #pragma unroll
      for (int kk = 0; kk < 2; ++kk)
        af[mi][kk] = *(const short8*)(Ah + row * 64 + (((kk * 4 + quad) ^ (row & 7)) << 3));
    }
    #pragma unroll
    for (int ni = 0; ni < 2; ++ni) {
      const int row = brb + ni * 16 + l15;
      #pragma unroll
      for (int kk = 0; kk < 2; ++kk)
        b0[ni][kk] = *(const short8*)(Bh + row * 64 + (((kk * 4 + quad) ^ (row & 7)) << 3));
    }
    __builtin_amdgcn_s_barrier();
    __builtin_amdgcn_s_setprio(1);
    #pragma unroll
    for (int mi = 0; mi < 4; ++mi)
      #pragma unroll
      for (int ni = 0; ni < 2; ++ni)
        #pragma unroll
        for (int kk = 0; kk < 2; ++kk)
          acc[mi][ni] = __builtin_amdgcn_mfma_f32_16x16x32_bf16(af[mi][kk], b0[ni][kk], acc[mi][ni], 0, 0, 0);
    __builtin_amdgcn_s_setprio(0);
    __builtin_amdgcn_s_barrier();

    #pragma unroll
    for (int ni = 0; ni < 2; ++ni) {
      const int row = brb + (ni + 2) * 16 + l15;
      #pragma unroll
      for (int kk = 0; kk < 2; ++kk)
        b1[ni][kk] = *(const short8*)(Bh + row * 64 + (((kk * 4 + quad) ^ (row & 7)) << 3));
    }
    __builtin_amdgcn_s_barrier();
    __builtin_amdgcn_s_setprio(1);
    #pragma unroll
    for (int mi = 0; mi < 4; ++mi)
      #pragma unroll
      for (int ni = 0; ni < 2; ++ni)
        #pragma unroll
        for (int kk = 0; kk < 2; ++kk)
          acc[mi][ni + 2] = __builtin_amdgcn_mfma_f32_16x16x32_bf16(af[mi][kk], b1[ni][kk], acc[mi][ni + 2], 0, 0, 0);
    __builtin_amdgcn_s_setprio(0);
    __builtin_amdgcn_s_barrier();

    #pragma unroll
    for (int mi = 0; mi < 4; ++mi) {
      const int row = (mi + 4) * 16 + l15;
      #pragma unroll
      for (int kk = 0; kk < 2; ++kk)
        af[mi][kk] = *(const short8*)(Ah + row * 64 + (((kk * 4 + quad) ^ (row & 7)) << 3));
    }
    __builtin_amdgcn_s_barrier();
    __builtin_amdgcn_s_setprio(1);
    #pragma unroll
    for (int mi = 0; mi < 4; ++mi)
      #pragma unroll
      for (int ni = 0; ni < 2; ++ni)
        #pragma unroll
        for (int kk = 0; kk < 2; ++kk)
          acc[mi + 4][ni + 2] = __builtin_amdgcn_mfma_f32_16x16x32_bf16(af[mi][kk], b1[ni][kk], acc[mi + 4][ni + 2], 0, 0, 0);
    __builtin_amdgcn_s_setprio(0);
    __builtin_amdgcn_s_barrier();

    __builtin_amdgcn_s_setprio(1);
    #pragma unroll
    for (int mi = 0; mi < 4; ++mi)
      #pragma unroll
      for (int ni = 0; ni < 2; ++ni)
        #pragma unroll
        for (int kk = 0; kk < 2; ++kk)
          acc[mi + 4][ni] = __builtin_amdgcn_mfma_f32_16x16x32_bf16(af[mi][kk], b0[ni][kk], acc[mi + 4][ni], 0, 0, 0);
    __builtin_amdgcn_s_setprio(0);
    __syncthreads();
  }

  unsigned short* Cw = (w < 4) ? ((unsigned short*)As + w * 8192)
                               : ((unsigned short*)Bs + (w - 4) * 8192);
  const int pc = lc8 ^ lr8;

  if (z < 2) {
    unsigned short* outp = z ? Kp : Qp;
    const int n0 = blockN + wn * 64;
    const int m0 = blockM + wm * 128;
    float bn[4];
    #pragma unroll
    for (int ni = 0; ni < 4; ++ni) bn[ni] = bias[n0 + ni * 16 + l15];
    #pragma unroll
    for (int mi = 0; mi < 8; ++mi)
      #pragma unroll
      for (int ni = 0; ni < 4; ++ni)
        #pragma unroll
        for (int rr = 0; rr < 4; ++rr) {
          const int row = mi * 16 + quad * 4 + rr;
          const int col = ni * 16 + l15;
          Cw[row * 64 + (((col >> 3) ^ (row & 7)) << 3) + (col & 7)] =
              f32_bf16(acc[mi][ni][rr] + bn[ni]);
        }
    const size_t bb = (size_t)(m0 >> 11);
    const int h = n0 >> 6, s0 = m0 & 2047;
    unsigned short* dst = outp + ((bb * 16 + h) * 2048 + s0) * 64;
    #pragma unroll
    for (int ps = 0; ps < 16; ++ps) {
      const int lr = ps * 8 + lr8;
      *(short8*)(dst + lr * 64 + lc8 * 8) = *(const short8*)(Cw + lr * 64 + pc * 8);
    }
  } else {
    const int m0 = blockM + wm * 128;
    const int n0 = blockN + wn * 64;
    #pragma unroll
    for (int mi = 0; mi < 8; ++mi) {
      float bm[4];
      #pragma unroll
      for (int rr = 0; rr < 4; ++rr) bm[rr] = bias[m0 + mi * 16 + quad * 4 + rr];
      #pragma unroll
      for (int ni = 0; ni < 4; ++ni)
        #pragma unroll
        for (int rr = 0; rr < 4; ++rr) {
          const int row = mi * 16 + quad * 4 + rr;
          const int col = ni * 16 + l15;
          Cw[row * 64 + (((col >> 3) ^ (row & 7)) << 3) + (col & 7)] =
              f32_bf16(acc[mi][ni][rr] + bm[rr]);
        }
    }
    const size_t bb = (size_t)(n0 >> 11);
    const int s0 = n0 & 2047;
    unsigned short* dst = Vt + (bb * 1024 + m0) * 2048 + s0;
    #pragma unroll
    for (int ps = 0; ps < 16; ++ps) {
      const int lr = ps * 8 + lr8;
      *(short8*)(dst + (size_t)lr * 2048 + lc8 * 8) = *(const short8*)(Cw + lr * 64 + pc * 8);
    }
  }
}

// ---------------- output projection: 128x64 tiles, BK=64, swizzled LDS ----------------

__global__ __launch_bounds__(256) void gemm_out_kernel(
    const unsigned short* __restrict__ A, const unsigned short* __restrict__ Bt,
    const float* __restrict__ bias, float* __restrict__ out, int K, int N) {
  __shared__ unsigned short As[2][128 * 64];
  __shared__ unsigned short Bs[2][64 * 64];
  const int tid = threadIdx.x;
  const int w = tid >> 6, lane = tid & 63;
  const int quad = lane >> 4, l15 = lane & 15;
  const int wm = w & 1, wn = w >> 1;
  const int lr8 = lane >> 3, lc8 = lane & 7;
  const int gcs = lc8 ^ lr8;
  const int l = blockIdx.x, r = l & 7, j = l >> 3;
  const int blockM = (r * 4 + (j & 3)) * 128;
  const int blockN = (j >> 2) * 64;

  floatx4 acc[4][2];
  #pragma unroll
  for (int mi = 0; mi < 4; ++mi)
    #pragma unroll
    for (int ni = 0; ni < 2; ++ni)
      acc[mi][ni] = (floatx4){0.f, 0.f, 0.f, 0.f};

  auto stage = [&](int k0, int buf) {
    #pragma unroll
    for (int i = 0; i < 4; ++i) {
      const int rl = w * 32 + i * 8;
      gld16(A + (size_t)(blockM + rl + lr8) * K + k0 + gcs * 8, As[buf] + rl * 64);
    }
    #pragma unroll
    for (int i = 0; i < 2; ++i) {
      const int rl = w * 16 + i * 8;
      gld16(Bt + (size_t)(blockN + rl + lr8) * K + k0 + gcs * 8, Bs[buf] + rl * 64);
    }
  };

  const int iters = K >> 6;
  stage(0, 0);
  for (int it = 0; it < iters; ++it) {
    __syncthreads();
    if (it + 1 < iters) stage((it + 1) * 64, (it + 1) & 1);
    const unsigned short* Asb = As[it & 1];
    const unsigned short* Bsb = Bs[it & 1];
    short8 bf[2][2];
    #pragma unroll
    for (int ni = 0; ni < 2; ++ni) {
      const int row = wn * 32 + ni * 16 + l15;
      #pragma unroll
      for (int kk = 0; kk < 2; ++kk)
        bf[ni][kk] = *(const short8*)(Bsb + row * 64 + (((kk * 4 + quad) ^ (row & 7)) << 3));
    }
    #pragma unroll
    for (int mi = 0; mi < 4; ++mi) {
      const int row = wm * 64 + mi * 16 + l15;
      #pragma unroll
      for (int kk = 0; kk < 2; ++kk) {
        short8 af = *(const short8*)(Asb + row * 64 + (((kk * 4 + quad) ^ (row & 7)) << 3));
        #pragma unroll
        for (int ni = 0; ni < 2; ++ni)
          acc[mi][ni] = __builtin_amdgcn_mfma_f32_16x16x32_bf16(af, bf[ni][kk], acc[mi][ni], 0, 0, 0);
      }
    }
  }

  #pragma unroll
  for (int mi = 0; mi < 4; ++mi)
    #pragma unroll
    for (int ni = 0; ni < 2; ++ni) {
      const int n = blockN + wn * 32 + ni * 16 + l15;
      const float bv = bias[n];
      #pragma unroll
      for (int rr = 0; rr < 4; ++rr) {
        const int m = blockM + wm * 64 + mi * 16 + quad * 4 + rr;
        out[(size_t)m * N + n] = acc[mi][ni][rr] + bv;
      }
    }
}

// ---------------- flash attention: KVBLK=64, 50KB LDS, pad-72 P ----------------
// Q,K: bf16 [BH][S][64]; Vt: bf16 [BH][64][S]; ctx: bf16 [B][S][1024]
// Swapped QK^T (mfma(K,Q)): lane = q (l15), regs = 4 consecutive keys.
// P -> LDS [32 q][72] (pad kills bank conflicts, no swizzle needed),
// truncation pack, b64 stores; lsum from the same truncated weights.

__global__ __launch_bounds__(256) void attn_kernel(
    const unsigned short* __restrict__ Q, const unsigned short* __restrict__ Kg,
    const unsigned short* __restrict__ Vt, const float* __restrict__ maskAdd,
    unsigned short* __restrict__ ctx) {
  const int S = 2048;
  const int tid = threadIdx.x;
  const int w = tid >> 6, lane = tid & 63, quad = lane >> 4, l15 = lane & 15;
  const int l = blockIdx.x, r8 = l & 7, j8 = l >> 3;
  const int bh = r8 * 4 + (j8 & 3);
  const int qb = j8 >> 2;
  const int b = bh >> 4, h = bh & 15;
  const int q0 = qb * 128;

  __shared__ unsigned short Ks[2][64 * 64];   // [key][e], 8-chunk rows, XOR swz
  __shared__ unsigned short Vs[2][64 * 64];   // [e][key], 8-chunk rows, XOR swz
  __shared__ unsigned short Ps[4][32 * 72];   // per-wave [q][key64], pad-72
  unsigned short* Pw = Ps[w];

  const unsigned short* Qb = Q + (size_t)bh * S * 64;
  const unsigned short* Kb = Kg + (size_t)bh * S * 64;
  const unsigned short* Vb = Vt + (size_t)bh * 64 * S;
  const float* mb = maskAdd + (size_t)b * S;

  const float qs = 0.125f * LOG2E;
  short8 qf[2][2];
  #pragma unroll
  for (int mi = 0; mi < 2; ++mi)
    #pragma unroll
    for (int kq = 0; kq < 2; ++kq) {
      short8 v = *(const short8*)(Qb + (size_t)(q0 + w * 32 + mi * 16 + l15) * 64 + kq * 32 + quad * 8);
      #pragma unroll
      for (int jj = 0; jj < 8; ++jj)
        v[jj] = (short)f32_bf16(bf16_f32((unsigned short)v[jj]) * qs);
      qf[mi][kq] = v;
    }

  floatx4 O[2][4];
  float lsum[2] = {0.f, 0.f};
  #pragma unroll
  for (int mi = 0; mi < 2; ++mi)
    #pragma unroll
    for (int ne = 0; ne < 4; ++ne) O[mi][ne] = (floatx4){0.f, 0.f, 0.f, 0.f};

  auto stage_kv = [&](int t, int buf) {
    const int kv0 = t * 64;
    #pragma unroll
    for (int i = 0; i < 2; ++i) {   // K tile [64 key][64 e]
      int r0 = w * 16 + i * 8;
      int row = r0 + (lane >> 3);
      int cg = (lane & 7) ^ (row & 7);
      gld16(Kb + (size_t)(kv0 + row) * 64 + cg * 8, Ks[buf] + r0 * 64);
    }
    #pragma unroll
    for (int i = 0; i < 2; ++i) {   // V tile [64 e][64 key]
      int r0 = w * 16 + i * 8;
      int row = r0 + (lane >> 3);
      int cg = (lane & 7) ^ (row & 7);
      gld16(Vb + (size_t)row * S + kv0 + cg * 8, Vs[buf] + r0 * 64);
    }
  };

  stage_kv(0, 0);
  for (int t = 0; t < 32; ++t) {
    const int kv0 = t * 64;
    __syncthreads();  // drains stage(t); publishes buf t&1
    if (t + 1 < 32) stage_kv(t + 1, (t + 1) & 1);
    const unsigned short* Ksb = Ks[t & 1];
    const unsigned short* Vsb = Vs[t & 1];

    // QK^T (swapped: C[key][q]) + exp2 + truncation pack -> P LDS [q][key]
    #pragma unroll
    for (int ni = 0; ni < 4; ++ni) {
      const int key16 = ni * 16;
      const int krow = key16 + l15;
      short8 kf0 = *(const short8*)(Ksb + krow * 64 + ((quad ^ (l15 & 7)) * 8));
      short8 kf1 = *(const short8*)(Ksb + krow * 64 + (((4 + quad) ^ (l15 & 7)) * 8));
      const floatx4 m4 = *(const floatx4*)(mb + kv0 + key16 + quad * 4);
      const int c = ni * 2 + (quad >> 1);       // 16B chunk within P row
      #pragma unroll
      for (int mi = 0; mi < 2; ++mi) {
        floatx4 s = (floatx4){0.f, 0.f, 0.f, 0.f};
        s = __builtin_amdgcn_mfma_f32_16x16x32_bf16(kf0, qf[mi][0], s, 0, 0, 0);
        s = __builtin_amdgcn_mfma_f32_16x16x32_bf16(kf1, qf[mi][1], s, 0, 0, 0);
        short4v pk;
        #pragma unroll
        for (int rr = 0; rr < 4; ++rr) {
          const float p = __builtin_amdgcn_exp2f(s[rr] + m4[rr]);
          union { float f; unsigned u; } cc; cc.f = p;
          pk[rr] = (short)(cc.u >> 16);          // truncation pack (R6-proven)
          union { unsigned u; float f; } dd; dd.u = cc.u & 0xFFFF0000u;
          lsum[mi] += dd.f;                      // same truncated weights
        }
        *(short4v*)(Pw + (mi * 16 + l15) * 72 + c * 8 + (quad & 1) * 4) = pk;
      }
    }
    asm volatile("" ::: "memory");  // P stores ordered before PV reads
    // PV
    #pragma unroll
    for (int kkl = 0; kkl < 2; ++kkl) {
      short8 pfr[2], vfr[4];
      #pragma unroll
      for (int mi = 0; mi < 2; ++mi)
        pfr[mi] = *(const short8*)(Pw + (mi * 16 + l15) * 72 + (kkl * 4 + quad) * 8);
      #pragma unroll
      for (int ne = 0; ne < 4; ++ne) {
        const int vrow = ne * 16 + l15;
        vfr[ne] = *(const short8*)(Vsb + vrow * 64 + (((kkl * 4 + quad) ^ (l15 & 7)) * 8));
      }
      #pragma unroll
      for (int mi = 0; mi < 2; ++mi)
        #pragma unroll
        for (int ne = 0; ne < 4; ++ne)
          O[mi][ne] = __builtin_amdgcn_mfma_f32_16x16x32_bf16(pfr[mi], vfr[ne], O[mi][ne], 0, 0, 0);
    }
    asm volatile("" ::: "memory");  // PV reads ordered before next-t stores
  }

  // epilogue: reduce row-sums across quads, redistribute 1/l, store ctx
  #pragma unroll
  for (int mi = 0; mi < 2; ++mi) {
    float v = lsum[mi];
    v += __shfl_xor(v, 16);
    v += __shfl_xor(v, 32);
    #pragma unroll
    for (int rr = 0; rr < 4; ++rr) {
      const float lv = __shfl(v, quad * 4 + rr);
      const float inv = __builtin_amdgcn_rcpf(lv);
      const int s = q0 + w * 32 + mi * 16 + quad * 4 + rr;
      #pragma unroll
      for (int ne = 0; ne < 4; ++ne)
        ctx[((size_t)b * S + s) * 1024 + h * 64 + ne * 16 + l15] = f32_bf16(O[mi][ne][rr] * inv);
    }
  }
}

// ---------------- host ----------------

extern "C" void kernel_launch(void* const* d_in, const int* in_sizes, int n_in,
                              void* d_out, int out_size, void* d_ws, size_t ws_size,
                              hipStream_t stream) {
  const float* query = (const float*)d_in[0];
  const float* key   = (const float*)d_in[1];
  const float* value = (const float*)d_in[2];
  const int*   mask  = (const int*)d_in[3];
  const float* Wq = (const float*)d_in[4];
  const float* bq = (const float*)d_in[5];
  const float* Wk = (const float*)d_in[6];
  const float* bk = (const float*)d_in[7];
  const float* Wv = (const float*)d_in[8];
  const float* bv = (const float*)d_in[9];
  const float* Wo = (const float*)d_in[10];
  const float* bo = (const float*)d_in[11];
  float* out = (float*)d_out;

  char* ws = (char*)d_ws;
  const size_t MB = 1024 * 1024;
  unsigned short* qin  = (unsigned short*)(ws + 0);        // 8MB
  unsigned short* kin  = (unsigned short*)(ws + 8 * MB);   // 8MB
  unsigned short* vin  = (unsigned short*)(ws + 16 * MB);  // 8MB
  unsigned short* WqT  = (unsigned short*)(ws + 24 * MB);  // 2MB
  unsigned short* WkT  = (unsigned short*)(ws + 26 * MB);
  unsigned short* WvT  = (unsigned short*)(ws + 28 * MB);
  unsigned short* WoT  = (unsigned short*)(ws + 30 * MB);
  unsigned short* Qp   = (unsigned short*)(ws + 32 * MB);  // 8MB [BH][S][64]
  unsigned short* Kp   = (unsigned short*)(ws + 40 * MB);  // 8MB [BH][S][64]
  unsigned short* Vt   = (unsigned short*)(ws + 48 * MB);  // 8MB [BH][64][S]
  float* maskAdd       = (float*)(ws + 56 * MB);           // 16KB
  unsigned short* ctxb = qin;  // alias: qin consumed by proj before attn writes ctx

  prep_kernel<<<dim3(4096, 4), 256, 0, stream>>>(query, key, value, Wq, Wk, Wv, Wo, mask,
                                                 qin, kin, vin, WqT, WkT, WvT, WoT, maskAdd);
  gemm_proj_kernel<<<dim3(64, 3), 512, 0, stream>>>(qin, kin, vin, WqT, WkT, WvT,
                                                    bq, bk, bv, Qp, Kp, Vt);
  attn_kernel<<<dim3(512), 256, 0, stream>>>(Qp, Kp, Vt, maskAdd, ctxb);
  gemm_out_kernel<<<dim3(512), 256, 0, stream>>>(ctxb, WoT, bo, out, 1024, 1024);
}

// Round 10
// 229.440 us; speedup vs baseline: 1.0641x; 1.0641x over previous
//
#include <hip/hip_runtime.h>
#include <stdint.h>
#include <math.h>

// MultiHeadAttention: B=2, S=2048, D=1024, H=16, DH=64
// R14 (resubmit; previous round failed on container acquisition, not kernel)
// = consolidation of validated-only parts (R13's post-timing divergence
// proved the swapped-QK attn family has an intermittent race; every failing
// round R8/R9/R12/R13 was that family, every passing round R6/R7/R10/R11 was
// not or had a different softmax path):
//  - attn: exact R6/R7 attention (KVBLK=128, mfma(Q,K), mfma-ones denom,
//    scattered P stores) -- 58.9us, replay-validated twice.
//  - proj: R7 256x256 deep-pipelined (validated R7/R10/R11).
//  - gemm_out: BK=64 + XOR chunk swizzle (validated R10/R11, ~3us faster).
//  - prep unchanged.

typedef __attribute__((ext_vector_type(8))) short short8;
typedef __attribute__((ext_vector_type(4))) float floatx4;

#define LOG2E 1.44269504088896340736f

__device__ __forceinline__ unsigned short f32_bf16(float f) {
  union { float f; unsigned u; } c; c.f = f;
  return (unsigned short)((c.u + 0x7FFFu + ((c.u >> 16) & 1u)) >> 16);
}
__device__ __forceinline__ float bf16_f32(unsigned short u) {
  union { unsigned u; float f; } c; c.u = ((unsigned)u) << 16;
  return c.f;
}
__device__ __forceinline__ void gld16(const void* g, void* l) {
  __builtin_amdgcn_global_load_lds((const __attribute__((address_space(1))) void*)g,
                                   (__attribute__((address_space(3))) void*)l, 16, 0, 0);
}

// ---------------- prep: cvt inputs + weight transposes + mask, one launch ----------------

__global__ __launch_bounds__(256) void prep_kernel(
    const float* __restrict__ qf, const float* __restrict__ kf, const float* __restrict__ vf,
    const float* __restrict__ w0, const float* __restrict__ w1, const float* __restrict__ w2,
    const float* __restrict__ wo, const int* __restrict__ mask,
    unsigned short* __restrict__ oq, unsigned short* __restrict__ ok, unsigned short* __restrict__ ov,
    unsigned short* __restrict__ o0, unsigned short* __restrict__ o1, unsigned short* __restrict__ o2,
    unsigned short* __restrict__ oo, float* __restrict__ mb) {
  __shared__ float t[32][33];
  const int y = blockIdx.y, bx = blockIdx.x;
  if (y < 3) {
    if (y == 0 && bx < 16) {
      int j = bx * 256 + threadIdx.x;
      mb[j] = (mask[j] == 0) ? (-1.0e9f * LOG2E) : 0.0f;
    }
    const float* in = (y == 0) ? qf : (y == 1) ? kf : vf;
    unsigned short* out = (y == 0) ? oq : (y == 1) ? ok : ov;
    int i = bx * 256 + threadIdx.x;
    float4 v = reinterpret_cast<const float4*>(in)[i];
    ushort4 o;
    o.x = f32_bf16(v.x); o.y = f32_bf16(v.y); o.z = f32_bf16(v.z); o.w = f32_bf16(v.w);
    reinterpret_cast<ushort4*>(out)[i] = o;
    return;
  }
  const int tx = threadIdx.x & 31, ty = threadIdx.x >> 5;
  const float* in; unsigned short* out; int R, C, z, r0, c0;
  if (bx < 3072) {
    const int zb = bx >> 6, rem = bx & 63;
    const int sel = zb >> 4; z = zb & 15;
    in = (sel == 0) ? w0 : (sel == 1) ? w1 : w2;
    out = (sel == 0) ? o0 : (sel == 1) ? o1 : o2;
    R = 1024; C = 64; r0 = (rem >> 1) * 32; c0 = (rem & 1) * 32;
  } else {
    const int t2 = bx - 3072;
    in = wo; out = oo; R = 1024; C = 1024; z = 0;
    r0 = (t2 >> 5) * 32; c0 = (t2 & 31) * 32;
  }
  const float* inp = in + (size_t)z * R * C;
  #pragma unroll
  for (int j = 0; j < 4; ++j)
    t[ty + j * 8][tx] = inp[(size_t)(r0 + ty + j * 8) * C + c0 + tx];
  __syncthreads();
  #pragma unroll
  for (int j = 0; j < 4; ++j)
    out[((size_t)z * C + c0 + ty + j * 8) * R + r0 + tx] = f32_bf16(t[tx][ty + j * 8]);
}

// ---------------- 256x256 deep-pipelined projection GEMM (R7, validated) ----------------

__global__ __launch_bounds__(512, 2) void gemm_proj_kernel(
    const unsigned short* __restrict__ qin, const unsigned short* __restrict__ kin,
    const unsigned short* __restrict__ vin,
    const unsigned short* __restrict__ WqT, const unsigned short* __restrict__ WkT,
    const unsigned short* __restrict__ WvT,
    const float* __restrict__ bq, const float* __restrict__ bk, const float* __restrict__ bv,
    unsigned short* __restrict__ Qp, unsigned short* __restrict__ Kp,
    unsigned short* __restrict__ Vt) {
  __shared__ unsigned short As[2][2][128 * 64];
  __shared__ unsigned short Bs[2][2][128 * 64];

  const int z = blockIdx.y;
  const int x = blockIdx.x;
  const int r = x & 7, q = x >> 3;
  int mt, nt;
  if (z < 2) { mt = r * 2 + (q >> 2); nt = q & 3; }
  else       { nt = r * 2 + (q >> 2); mt = q & 3; }
  const int blockM = mt * 256, blockN = nt * 256;

  const unsigned short* A  = (z == 0) ? qin : (z == 1) ? kin : WvT;
  const unsigned short* Bt = (z == 0) ? WqT : (z == 1) ? WkT : vin;
  const float* bias = (z == 0) ? bq : (z == 1) ? bk : bv;

  const int tid = threadIdx.x;
  const int w = tid >> 6, lane = tid & 63;
  const int quad = lane >> 4, l15 = lane & 15;
  const int wm = w & 1, wn = w >> 1;

  const int lr8 = lane >> 3;
  const int lc8 = lane & 7;
  const int gcs = lc8 ^ lr8;

  auto stage = [&](int k0, int buf) {
    #pragma unroll
    for (int h = 0; h < 2; ++h)
      #pragma unroll
      for (int s2 = 0; s2 < 2; ++s2) {
        const int rl = s2 * 64 + w * 8;
        gld16(A + (size_t)(blockM + h * 128 + rl + lr8) * 1024 + k0 + gcs * 8,
              &As[buf][h][rl * 64]);
      }
    #pragma unroll
    for (int h = 0; h < 2; ++h)
      #pragma unroll
      for (int s2 = 0; s2 < 2; ++s2) {
        const int rl = s2 * 64 + w * 8;
        gld16(Bt + (size_t)(blockN + h * 128 + rl + lr8) * 1024 + k0 + gcs * 8,
              &Bs[buf][h][rl * 64]);
      }
  };

  floatx4 acc[8][4];
  #pragma unroll
  for (int mi = 0; mi < 8; ++mi)
    #pragma unroll
    for (int ni = 0; ni < 4; ++ni)
      acc[mi][ni] = (floatx4){0.f, 0.f, 0.f, 0.f};

  stage(0, 0);
  __syncthreads();

  const int brb = (wn & 1) * 64;

  for (int st = 0; st < 16; ++st) {
    const int buf = st & 1;
    const unsigned short* Ah = &As[buf][wm][0];
    const unsigned short* Bh = &Bs[buf][wn >> 1][0];
    short8 af[4][2], b0[2][2], b1[2][2];

    if (st + 1 < 16) stage((st + 1) * 64, buf ^ 1);
    #pragma unroll
    for (int mi = 0; mi < 4; ++mi) {
      const int row = mi * 16 + l15;
      #pragma unroll
      for (int kk = 0; kk < 2; ++kk)
        af[mi][kk] = *(const short8*)(Ah + row * 64 + (((kk * 4 + quad) ^ (row & 7)) << 3));
    }
    #pragma unroll
    for (int ni = 0; ni < 2; ++ni) {
      const int row = brb + ni * 16 + l15;
      #pragma unroll
      for (int kk = 0; kk < 2; ++kk)
        b0[ni][kk] = *(const short8*)(Bh + row * 64 + (((kk * 4 + quad) ^ (row & 7)) << 3));
    }
    __builtin_amdgcn_s_barrier();
    __builtin_amdgcn_s_setprio(1);
    #pragma unroll
    for (int mi = 0; mi < 4; ++mi)
      #pragma unroll
      for (int ni = 0; ni < 2; ++ni)
        #pragma unroll
        for (int kk = 0; kk < 2; ++kk)
          acc[mi][ni] = __builtin_amdgcn_mfma_f32_16x16x32_bf16(af[mi][kk], b0[ni][kk], acc[mi][ni], 0, 0, 0);
    __builtin_amdgcn_s_setprio(0);
    __builtin_amdgcn_s_barrier();

    #pragma unroll
    for (int ni = 0; ni < 2; ++ni) {
      const int row = brb + (ni + 2) * 16 + l15;
      #pragma unroll
      for (int kk = 0; kk < 2; ++kk)
        b1[ni][kk] = *(const short8*)(Bh + row * 64 + (((kk * 4 + quad) ^ (row & 7)) << 3));
    }
    __builtin_amdgcn_s_barrier();
    __builtin_amdgcn_s_setprio(1);
    #pragma unroll
    for (int mi = 0; mi < 4; ++mi)
      #pragma unroll
      for (int ni = 0; ni < 2; ++ni)
        #pragma unroll
        for (int kk = 0; kk < 2; ++kk)
          acc[mi][ni + 2] = __builtin_amdgcn_mfma_f32_16x16x32_bf16(af[mi][kk], b1[ni][kk], acc[mi][ni + 2], 0, 0, 0);
    __builtin_amdgcn_s_setprio(0);
    __builtin_amdgcn_s_barrier();

    #pragma unroll
    for (int mi = 0; mi < 4; ++mi) {
      const int row = (mi + 4) * 16 + l15;
      #pragma unroll
      for (int kk = 0; kk < 2; ++kk)
        af[mi][kk] = *(const short8*)(Ah + row * 64 + (((kk * 4 + quad) ^ (row & 7)) << 3));
    }
    __builtin_amdgcn_s_barrier();
    __builtin_amdgcn_s_setprio(1);
    #pragma unroll
    for (int mi = 0; mi < 4; ++mi)
      #pragma unroll
      for (int ni = 0; ni < 2; ++ni)
        #pragma unroll
        for (int kk = 0; kk < 2; ++kk)
          acc[mi + 4][ni + 2] = __builtin_amdgcn_mfma_f32_16x16x32_bf16(af[mi][kk], b1[ni][kk], acc[mi + 4][ni + 2], 0, 0, 0);
    __builtin_amdgcn_s_setprio(0);
    __builtin_amdgcn_s_barrier();

    __builtin_amdgcn_s_setprio(1);
    #pragma unroll
    for (int mi = 0; mi < 4; ++mi)
      #pragma unroll
      for (int ni = 0; ni < 2; ++ni)
        #pragma unroll
        for (int kk = 0; kk < 2; ++kk)
          acc[mi + 4][ni] = __builtin_amdgcn_mfma_f32_16x16x32_bf16(af[mi][kk], b0[ni][kk], acc[mi + 4][ni], 0, 0, 0);
    __builtin_amdgcn_s_setprio(0);
    __syncthreads();
  }

  unsigned short* Cw = (w < 4) ? ((unsigned short*)As + w * 8192)
                               : ((unsigned short*)Bs + (w - 4) * 8192);
  const int pc = lc8 ^ lr8;

  if (z < 2) {
    unsigned short* outp = z ? Kp : Qp;
    const int n0 = blockN + wn * 64;
    const int m0 = blockM + wm * 128;
    float bn[4];
    #pragma unroll
    for (int ni = 0; ni < 4; ++ni) bn[ni] = bias[n0 + ni * 16 + l15];
    #pragma unroll
    for (int mi = 0; mi < 8; ++mi)
      #pragma unroll
      for (int ni = 0; ni < 4; ++ni)
        #pragma unroll
        for (int rr = 0; rr < 4; ++rr) {
          const int row = mi * 16 + quad * 4 + rr;
          const int col = ni * 16 + l15;
          Cw[row * 64 + (((col >> 3) ^ (row & 7)) << 3) + (col & 7)] =
              f32_bf16(acc[mi][ni][rr] + bn[ni]);
        }
    const size_t bb = (size_t)(m0 >> 11);
    const int h = n0 >> 6, s0 = m0 & 2047;
    unsigned short* dst = outp + ((bb * 16 + h) * 2048 + s0) * 64;
    #pragma unroll
    for (int ps = 0; ps < 16; ++ps) {
      const int lr = ps * 8 + lr8;
      *(short8*)(dst + lr * 64 + lc8 * 8) = *(const short8*)(Cw + lr * 64 + pc * 8);
    }
  } else {
    const int m0 = blockM + wm * 128;
    const int n0 = blockN + wn * 64;
    #pragma unroll
    for (int mi = 0; mi < 8; ++mi) {
      float bm[4];
      #pragma unroll
      for (int rr = 0; rr < 4; ++rr) bm[rr] = bias[m0 + mi * 16 + quad * 4 + rr];
      #pragma unroll
      for (int ni = 0; ni < 4; ++ni)
        #pragma unroll
        for (int rr = 0; rr < 4; ++rr) {
          const int row = mi * 16 + quad * 4 + rr;
          const int col = ni * 16 + l15;
          Cw[row * 64 + (((col >> 3) ^ (row & 7)) << 3) + (col & 7)] =
              f32_bf16(acc[mi][ni][rr] + bm[rr]);
        }
    }
    const size_t bb = (size_t)(n0 >> 11);
    const int s0 = n0 & 2047;
    unsigned short* dst = Vt + (bb * 1024 + m0) * 2048 + s0;
    #pragma unroll
    for (int ps = 0; ps < 16; ++ps) {
      const int lr = ps * 8 + lr8;
      *(short8*)(dst + (size_t)lr * 2048 + lc8 * 8) = *(const short8*)(Cw + lr * 64 + pc * 8);
    }
  }
}

// ---------------- output projection: 128x64 tiles, BK=64, swizzled LDS (R10/R11-validated) ----------------

__global__ __launch_bounds__(256) void gemm_out_kernel(
    const unsigned short* __restrict__ A, const unsigned short* __restrict__ Bt,
    const float* __restrict__ bias, float* __restrict__ out, int K, int N) {
  __shared__ unsigned short As[2][128 * 64];
  __shared__ unsigned short Bs[2][64 * 64];
  const int tid = threadIdx.x;
  const int w = tid >> 6, lane = tid & 63;
  const int quad = lane >> 4, l15 = lane & 15;
  const int wm = w & 1, wn = w >> 1;
  const int lr8 = lane >> 3, lc8 = lane & 7;
  const int gcs = lc8 ^ lr8;
  const int l = blockIdx.x, r = l & 7, j = l >> 3;
  const int blockM = (r * 4 + (j & 3)) * 128;
  const int blockN = (j >> 2) * 64;

  floatx4 acc[4][2];
  #pragma unroll
  for (int mi = 0; mi < 4; ++mi)
    #pragma unroll
    for (int ni = 0; ni < 2; ++ni)
      acc[mi][ni] = (floatx4){0.f, 0.f, 0.f, 0.f};

  auto stage = [&](int k0, int buf) {
    #pragma unroll
    for (int i = 0; i < 4; ++i) {
      const int rl = w * 32 + i * 8;
      gld16(A + (size_t)(blockM + rl + lr8) * K + k0 + gcs * 8, As[buf] + rl * 64);
    }
    #pragma unroll
    for (int i = 0; i < 2; ++i) {
      const int rl = w * 16 + i * 8;
      gld16(Bt + (size_t)(blockN + rl + lr8) * K + k0 + gcs * 8, Bs[buf] + rl * 64);
    }
  };

  const int iters = K >> 6;
  stage(0, 0);
  for (int it = 0; it < iters; ++it) {
    __syncthreads();
    if (it + 1 < iters) stage((it + 1) * 64, (it + 1) & 1);
    const unsigned short* Asb = As[it & 1];
    const unsigned short* Bsb = Bs[it & 1];
    short8 bf[2][2];
    #pragma unroll
    for (int ni = 0; ni < 2; ++ni) {
      const int row = wn * 32 + ni * 16 + l15;
      #pragma unroll
      for (int kk = 0; kk < 2; ++kk)
        bf[ni][kk] = *(const short8*)(Bsb + row * 64 + (((kk * 4 + quad) ^ (row & 7)) << 3));
    }
    #pragma unroll
    for (int mi = 0; mi < 4; ++mi) {
      const int row = wm * 64 + mi * 16 + l15;
      #pragma unroll
      for (int kk = 0; kk < 2; ++kk) {
        short8 af = *(const short8*)(Asb + row * 64 + (((kk * 4 + quad) ^ (row & 7)) << 3));
        #pragma unroll
        for (int ni = 0; ni < 2; ++ni)
          acc[mi][ni] = __builtin_amdgcn_mfma_f32_16x16x32_bf16(af, bf[ni][kk], acc[mi][ni], 0, 0, 0);
      }
    }
  }

  #pragma unroll
  for (int mi = 0; mi < 4; ++mi)
    #pragma unroll
    for (int ni = 0; ni < 2; ++ni) {
      const int n = blockN + wn * 32 + ni * 16 + l15;
      const float bv = bias[n];
      #pragma unroll
      for (int rr = 0; rr < 4; ++rr) {
        const int m = blockM + wm * 64 + mi * 16 + quad * 4 + rr;
        out[(size_t)m * N + n] = acc[mi][ni][rr] + bv;
      }
    }
}

// ---------------- flash attention (exact R6/R7 version, replay-validated) ----------------
// Q,K: bf16 [BH][S][64]; Vt: bf16 [BH][64][S]; ctx: bf16 [B][S][1024]

__global__ __launch_bounds__(256) void attn_kernel(
    const unsigned short* __restrict__ Q, const unsigned short* __restrict__ Kg,
    const unsigned short* __restrict__ Vt, const float* __restrict__ maskAdd,
    unsigned short* __restrict__ ctx) {
  const int S = 2048;
  const int tid = threadIdx.x;
  const int w = tid >> 6, lane = tid & 63, quad = lane >> 4, l15 = lane & 15;
  const int l = blockIdx.x, r8 = l & 7, j8 = l >> 3;
  const int bh = r8 * 4 + (j8 & 3);
  const int qb = j8 >> 2;
  const int b = bh >> 4, h = bh & 15;
  const int q0 = qb * 128;

  __shared__ unsigned short Ks[2][128 * 64];   // [key][e], swizzled, 8 chunks/row
  __shared__ unsigned short Vs[2][64 * 128];   // [e][key], swizzled, 16 chunks/row
  __shared__ unsigned short Ps[4][32 * 64];    // per-wave [q][key64], swizzled
  unsigned short* Pw = Ps[w];

  const unsigned short* Qb = Q + (size_t)bh * S * 64;
  const unsigned short* Kb = Kg + (size_t)bh * S * 64;
  const unsigned short* Vb = Vt + (size_t)bh * 64 * S;
  const float* mb = maskAdd + (size_t)b * S;

  const float qs = 0.125f * LOG2E;
  short8 qf[2][2];
  #pragma unroll
  for (int mi = 0; mi < 2; ++mi)
    #pragma unroll
    for (int kq = 0; kq < 2; ++kq) {
      short8 v = *(const short8*)(Qb + (size_t)(q0 + w * 32 + mi * 16 + l15) * 64 + kq * 32 + quad * 8);
      #pragma unroll
      for (int jj = 0; jj < 8; ++jj)
        v[jj] = (short)f32_bf16(bf16_f32((unsigned short)v[jj]) * qs);
      qf[mi][kq] = v;
    }

  short8 onesf;
  #pragma unroll
  for (int jj = 0; jj < 8; ++jj) onesf[jj] = (short)0x3F80;  // bf16 1.0

  floatx4 O[2][4], ls[2];
  #pragma unroll
  for (int mi = 0; mi < 2; ++mi) {
    #pragma unroll
    for (int ne = 0; ne < 4; ++ne) O[mi][ne] = (floatx4){0.f, 0.f, 0.f, 0.f};
    ls[mi] = (floatx4){0.f, 0.f, 0.f, 0.f};
  }

  auto stage_kv = [&](int t, int buf) {
    const int kv0 = t * 128;
    #pragma unroll
    for (int i = 0; i < 4; ++i) {  // K tile, swizzled source chunks
      int r0 = w * 32 + i * 8;
      int row = r0 + (lane >> 3);
      int cg = (lane & 7) ^ (row & 7);
      gld16(Kb + (size_t)(kv0 + row) * 64 + cg * 8, Ks[buf] + r0 * 64);
    }
    #pragma unroll
    for (int i = 0; i < 4; ++i) {  // V tile
      int r0 = w * 16 + i * 4;
      int row = r0 + (lane >> 4);
      int p = lane & 15;
      int cg = (p & 8) | ((p & 7) ^ (row & 7));
      gld16(Vb + (size_t)row * S + kv0 + cg * 8, Vs[buf] + r0 * 128);
    }
  };

  stage_kv(0, 0);
  for (int t = 0; t < 16; ++t) {
    const int kv0 = t * 128;
    __syncthreads();  // drains stage(t); publishes buf t&1
    float ma[8];
    #pragma unroll
    for (int ni = 0; ni < 8; ++ni) ma[ni] = mb[kv0 + ni * 16 + l15];
    if (t + 1 < 16) stage_kv(t + 1, (t + 1) & 1);
    const unsigned short* Ksb = Ks[t & 1];
    const unsigned short* Vsb = Vs[t & 1];

    #pragma unroll
    for (int ph = 0; ph < 2; ++ph) {
      floatx4 sc[2][4];
      #pragma unroll
      for (int ni = 0; ni < 4; ++ni) {
        const int key = (ph * 4 + ni) * 16 + l15;
        short8 kf0 = *(const short8*)(Ksb + key * 64 + ((quad) ^ (l15 & 7)) * 8);
        short8 kf1 = *(const short8*)(Ksb + key * 64 + ((4 + quad) ^ (l15 & 7)) * 8);
        #pragma unroll
        for (int mi = 0; mi < 2; ++mi) {
          floatx4 s = (floatx4){0.f, 0.f, 0.f, 0.f};
          s = __builtin_amdgcn_mfma_f32_16x16x32_bf16(qf[mi][0], kf0, s, 0, 0, 0);
          s = __builtin_amdgcn_mfma_f32_16x16x32_bf16(qf[mi][1], kf1, s, 0, 0, 0);
          sc[mi][ni] = s;
        }
      }
      #pragma unroll
      for (int mi = 0; mi < 2; ++mi)
        #pragma unroll
        for (int rr = 0; rr < 4; ++rr) {
          const int row = mi * 16 + quad * 4 + rr;
          const int g = (row + (row >> 3)) & 7;
          #pragma unroll
          for (int ni = 0; ni < 4; ++ni) {
            float p = __builtin_amdgcn_exp2f(sc[mi][ni][rr] + ma[ph * 4 + ni]);
            union { float f; unsigned u; } c; c.f = p;
            const int ch = (ni * 2 + (l15 >> 3)) ^ g;
            Pw[row * 64 + (ch & 7) * 8 + (l15 & 7)] = (unsigned short)(c.u >> 16);
          }
        }
      #pragma unroll
      for (int kkl = 0; kkl < 2; ++kkl) {
        const int kk = ph * 2 + kkl;
        short8 pfr[2], vfr[4];
        #pragma unroll
        for (int mi = 0; mi < 2; ++mi) {
          const int gp = (2 * mi + l15 + (l15 >> 3)) & 7;
          pfr[mi] = *(const short8*)(Pw + (mi * 16 + l15) * 64 + ((kkl * 4 + quad) ^ gp) * 8);
        }
        #pragma unroll
        for (int ne = 0; ne < 4; ++ne) {
          const int c = kk * 4 + quad;
          vfr[ne] = *(const short8*)(Vsb + (ne * 16 + l15) * 128 + ((c & 8) | ((c & 7) ^ (l15 & 7))) * 8);
        }
        #pragma unroll
        for (int mi = 0; mi < 2; ++mi) {
          #pragma unroll
          for (int ne = 0; ne < 4; ++ne)
            O[mi][ne] = __builtin_amdgcn_mfma_f32_16x16x32_bf16(pfr[mi], vfr[ne], O[mi][ne], 0, 0, 0);
          ls[mi] = __builtin_amdgcn_mfma_f32_16x16x32_bf16(pfr[mi], onesf, ls[mi], 0, 0, 0);
        }
      }
    }
  }

  // epilogue: ctx[b][s][h*64+e] = O / l
  #pragma unroll
  for (int mi = 0; mi < 2; ++mi)
    #pragma unroll
    for (int rr = 0; rr < 4; ++rr) {
      const float inv = __builtin_amdgcn_rcpf(ls[mi][rr]);
      const int s = q0 + w * 32 + mi * 16 + quad * 4 + rr;
      #pragma unroll
      for (int ne = 0; ne < 4; ++ne)
        ctx[((size_t)b * S + s) * 1024 + h * 64 + ne * 16 + l15] = f32_bf16(O[mi][ne][rr] * inv);
    }
}

// ---------------- host ----------------

extern "C" void kernel_launch(void* const* d_in, const int* in_sizes, int n_in,
                              void* d_out, int out_size, void* d_ws, size_t ws_size,
                              hipStream_t stream) {
  const float* query = (const float*)d_in[0];
  const float* key   = (const float*)d_in[1];
  const float* value = (const float*)d_in[2];
  const int*   mask  = (const int*)d_in[3];
  const float* Wq = (const float*)d_in[4];
  const float* bq = (const float*)d_in[5];
  const float* Wk = (const float*)d_in[6];
  const float* bk = (const float*)d_in[7];
  const float* Wv = (const float*)d_in[8];
  const float* bv = (const float*)d_in[9];
  const float* Wo = (const float*)d_in[10];
  const float* bo = (const float*)d_in[11];
  float* out = (float*)d_out;

  char* ws = (char*)d_ws;
  const size_t MB = 1024 * 1024;
  unsigned short* qin  = (unsigned short*)(ws + 0);        // 8MB
  unsigned short* kin  = (unsigned short*)(ws + 8 * MB);   // 8MB
  unsigned short* vin  = (unsigned short*)(ws + 16 * MB);  // 8MB
  unsigned short* WqT  = (unsigned short*)(ws + 24 * MB);  // 2MB
  unsigned short* WkT  = (unsigned short*)(ws + 26 * MB);
  unsigned short* WvT  = (unsigned short*)(ws + 28 * MB);
  unsigned short* WoT  = (unsigned short*)(ws + 30 * MB);
  unsigned short* Qp   = (unsigned short*)(ws + 32 * MB);  // 8MB [BH][S][64]
  unsigned short* Kp   = (unsigned short*)(ws + 40 * MB);  // 8MB [BH][S][64]
  unsigned short* Vt   = (unsigned short*)(ws + 48 * MB);  // 8MB [BH][64][S]
  float* maskAdd       = (float*)(ws + 56 * MB);           // 16KB
  unsigned short* ctxb = qin;  // alias: qin consumed by proj before attn writes ctx

  prep_kernel<<<dim3(4096, 4), 256, 0, stream>>>(query, key, value, Wq, Wk, Wv, Wo, mask,
                                                 qin, kin, vin, WqT, WkT, WvT, WoT, maskAdd);
  gemm_proj_kernel<<<dim3(64, 3), 512, 0, stream>>>(qin, kin, vin, WqT, WkT, WvT,
                                                    bq, bk, bv, Qp, Kp, Vt);
  attn_kernel<<<dim3(512), 256, 0, stream>>>(Qp, Kp, Vt, maskAdd, ctxb);
  gemm_out_kernel<<<dim3(512), 256, 0, stream>>>(ctxb, WoT, bo, out, 1024, 1024);
}